// Round 4
// baseline (1042.583 us; speedup 1.0000x reference)
//
#include <hip/hip_runtime.h>

// ---------------------------------------------------------------------------
// Round 8: pe is atomic-throughput-bound (occupancy 2x'd -> dur flat at
// ~230G atomics/s). Replace the 51.2M-atomicAdd scatter with CSR two-phase:
//  - pe writes new_edge bf16 coalesced (no atomics, no seg).
//  - CSR build: hist (400K int atomics) + 1-block scan + fill.
//  - k_mean: wave/node, sums CSR edge rows -> meanB bf16 (A-frag-ready).
//  - k_node reads meanB directly; seg/cnt gone from hot path.
//  - elB reverted (round 7: +102MB ee writes, no pe gain).
//  - ws guard: CSR needs 130.5MB; else fall back to round-6 atomic path.
// ---------------------------------------------------------------------------

#define N_NODES 50000
#define N_EDGES 400000
#define HID 128
#define LN_EPS 1e-5f

typedef unsigned short u16;
typedef __attribute__((ext_vector_type(8))) short short8;   // 8 x bf16
typedef __attribute__((ext_vector_type(4))) float floatx4;  // MFMA C/D

__device__ __forceinline__ u16 f2bf(float f) {
    union { float f; unsigned int i; } v; v.f = f;
    unsigned int x = v.i;
    return (u16)((x + 0x7FFFu + ((x >> 16) & 1u)) >> 16);  // RNE
}
__device__ __forceinline__ float bf2f(u16 u) {
    union { unsigned int i; float f; } v; v.i = ((unsigned int)u) << 16;
    return v.f;
}
__device__ __forceinline__ float siluf(float x) { return x * (1.0f / (1.0f + __expf(-x))); }
__device__ __forceinline__ float sigmf(float x) { return 1.0f / (1.0f + __expf(-x)); }

__device__ __forceinline__ short8 pack8(const float* __restrict__ p) {
    union { u16 u[8]; short8 v; } o;
    float4 a = *(const float4*)p;
    float4 b = *(const float4*)(p + 4);
    o.u[0] = f2bf(a.x); o.u[1] = f2bf(a.y); o.u[2] = f2bf(a.z); o.u[3] = f2bf(a.w);
    o.u[4] = f2bf(b.x); o.u[5] = f2bf(b.y); o.u[6] = f2bf(b.z); o.u[7] = f2bf(b.w);
    return o.v;
}
__device__ __forceinline__ short8 pack8s(const float* __restrict__ p, float sc) {
    union { u16 u[8]; short8 v; } o;
    float4 a = *(const float4*)p;
    float4 b = *(const float4*)(p + 4);
    o.u[0] = f2bf(a.x * sc); o.u[1] = f2bf(a.y * sc); o.u[2] = f2bf(a.z * sc); o.u[3] = f2bf(a.w * sc);
    o.u[4] = f2bf(b.x * sc); o.u[5] = f2bf(b.y * sc); o.u[6] = f2bf(b.z * sc); o.u[7] = f2bf(b.w * sc);
    return o.v;
}

// 256B-row LDS, 16B chunks XOR-swizzled by row
__device__ __forceinline__ char* swzp(const void* base, int row, int b) {
    return (char*)base + row * 256 + ((b & 15) | ((((b >> 4) ^ row) & 15) << 4));
}
// 128B-row LDS (64-col bf16), 16B chunks XOR-swizzled by row
__device__ __forceinline__ char* swz64(const void* base, int row, int b) {
    return (char*)base + row * 128 + ((b & 15) | ((((b >> 4) ^ row) & 7) << 4));
}

// W fp32 (K x N) row-major -> WT bf16 (N x K) row-major
__global__ void k_prepT(const float* __restrict__ src, u16* __restrict__ dst, int K, int N) {
    int i = blockIdx.x * blockDim.x + threadIdx.x;
    if (i < K * N) {
        int k = i / N, n = i - k * N;
        dst[n * K + k] = f2bf(src[i]);
    }
}

// ---------------- CSR build ------------------------------------------------
__global__ void k_hist(const int* __restrict__ eidx, int* __restrict__ icnt) {
    int e = blockIdx.x * blockDim.x + threadIdx.x;
    if (e < N_EDGES) atomicAdd(&icnt[eidx[e * 2 + 1]], 1);
}

__launch_bounds__(1024)
__global__ void k_scan(const int* __restrict__ icnt, int* __restrict__ offs) {
    __shared__ int s[1024];
    const int t = threadIdx.x;
    const int CH = 49;                       // 1024*49 >= 50000
    int base = t * CH;
    int sum = 0;
    for (int j = 0; j < CH; ++j) {
        int i = base + j;
        if (i < N_NODES) sum += icnt[i];
    }
    s[t] = sum;
    __syncthreads();
    for (int off = 1; off < 1024; off <<= 1) {
        int v = (t >= off) ? s[t - off] : 0;
        __syncthreads();
        s[t] += v;
        __syncthreads();
    }
    int run = s[t] - sum;                    // exclusive prefix of chunk
    for (int j = 0; j < CH; ++j) {
        int i = base + j;
        if (i < N_NODES) { offs[i] = run; run += icnt[i]; }
    }
    if (t == 1023) offs[N_NODES] = s[1023];
}

__global__ void k_fill(const int* __restrict__ eidx, const int* __restrict__ offs,
                       int* __restrict__ fpos, int* __restrict__ csr) {
    int e = blockIdx.x * blockDim.x + threadIdx.x;
    if (e < N_EDGES) {
        int r = eidx[e * 2 + 1];
        int p = atomicAdd(&fpos[r], 1);
        csr[offs[r] + p] = e;
    }
}

// ---------------- Stage 1: ee FFN + LN -> edge_lat (zero-barrier loop) -----
__launch_bounds__(256)
__global__ void k_edge_ee(const float* __restrict__ ef,
                          const float* __restrict__ W1, const float* __restrict__ b1v,
                          const u16* __restrict__ W2T, const float* __restrict__ b2v,
                          const float* __restrict__ g, const float* __restrict__ be,
                          float* __restrict__ outEL) {
    __shared__ __align__(16) u16 sW2[128 * 136];
    __shared__ float sW1[384];
    __shared__ float sB1[128];
    const int t = threadIdx.x;
    const int lane = t & 63, w = t >> 6;
    const int l15 = lane & 15, quad = lane >> 4;

    for (int i = t; i < 2048; i += 256) {
        int n = i >> 4, q = i & 15;
        *(uint4*)&sW2[n * 136 + q * 8] = *(const uint4*)&W2T[n * 128 + q * 8];
    }
    for (int i = t; i < 384; i += 256) sW1[i] = W1[i];
    if (t < 128) sB1[t] = b1v[t];
    __syncthreads();

    float b2r[8], gr[8], ber[8];
    #pragma unroll
    for (int nt = 0; nt < 8; ++nt) {
        int col = nt * 16 + l15;
        b2r[nt] = b2v[col]; gr[nt] = g[col]; ber[nt] = be[col];
    }

    for (int tile = blockIdx.x; tile < N_EDGES / 64; tile += gridDim.x) {
        const int e0 = tile * 64;
        const int em = e0 + w * 16 + l15;
        float f0 = ef[em * 3 + 0], f1 = ef[em * 3 + 1], f2 = ef[em * 3 + 2];
        short8 ha[4];
        #pragma unroll
        for (int ks = 0; ks < 4; ++ks) {
            union { u16 u[8]; short8 v; } hh;
            #pragma unroll
            for (int jj = 0; jj < 8; ++jj) {
                int j = ks * 32 + quad * 8 + jj;
                float x = sB1[j] + f0 * sW1[j] + f1 * sW1[128 + j] + f2 * sW1[256 + j];
                hh.u[jj] = f2bf(siluf(x));
            }
            ha[ks] = hh.v;
        }
        floatx4 acc[8];
        #pragma unroll
        for (int nt = 0; nt < 8; ++nt) acc[nt] = (floatx4){0.f, 0.f, 0.f, 0.f};
        #pragma unroll
        for (int ks = 0; ks < 4; ++ks) {
            #pragma unroll
            for (int nt = 0; nt < 8; ++nt) {
                short8 bv = *(const short8*)&sW2[(nt * 16 + l15) * 136 + ks * 32 + quad * 8];
                acc[nt] = __builtin_amdgcn_mfma_f32_16x16x32_bf16(ha[ks], bv, acc[nt], 0, 0, 0);
            }
        }
        float sum[4] = {0, 0, 0, 0}, sq[4] = {0, 0, 0, 0};
        #pragma unroll
        for (int nt = 0; nt < 8; ++nt)
            #pragma unroll
            for (int rr = 0; rr < 4; ++rr) {
                float v = acc[nt][rr] + b2r[nt];
                acc[nt][rr] = v; sum[rr] += v; sq[rr] += v * v;
            }
        #pragma unroll
        for (int m = 1; m < 16; m <<= 1)
            #pragma unroll
            for (int rr = 0; rr < 4; ++rr) {
                sum[rr] += __shfl_xor(sum[rr], m);
                sq[rr]  += __shfl_xor(sq[rr], m);
            }
        float mu[4], rs[4];
        #pragma unroll
        for (int rr = 0; rr < 4; ++rr) {
            mu[rr] = sum[rr] * (1.0f / HID);
            float var = fmaxf(sq[rr] * (1.0f / HID) - mu[rr] * mu[rr], 0.f);
            rs[rr] = rsqrtf(var + LN_EPS);
        }
        #pragma unroll
        for (int nt = 0; nt < 8; ++nt) {
            int col = nt * 16 + l15;
            #pragma unroll
            for (int rr = 0; rr < 4; ++rr) {
                int row = e0 + w * 16 + quad * 4 + rr;
                outEL[(size_t)row * HID + col] = (acc[nt][rr] - mu[rr]) * rs[rr] * gr[nt] + ber[nt];
            }
        }
    }
}

// ---------------- Dense helper: out = bf16(A @ W), PERMUTED row layout -----
// out[row][l15*8 + nt] = (A@W)[row][nt*16 + l15]
__launch_bounds__(256)
__global__ void k_gemm128(const float* __restrict__ A, const u16* __restrict__ WT,
                          int ldw, int koff, u16* __restrict__ out) {
    __shared__ __align__(16) u16 sW[128 * 128];
    const int t = threadIdx.x;
    const int lane = t & 63, w = t >> 6;
    const int l15 = lane & 15, quad = lane >> 4;
    for (int i = t; i < 2048; i += 256) {
        int n = i >> 4, q = i & 15;
        *(uint4*)swzp(sW, n, q * 16) = *(const uint4*)&WT[n * ldw + koff + q * 8];
    }
    __syncthreads();
    const int NT = (N_NODES + 63) / 64;
    for (int tile = blockIdx.x; tile < NT; tile += gridDim.x) {
        const int n0 = tile * 64;
        const int arow = n0 + w * 16 + l15;
        const int ac = arow < N_NODES ? arow : 0;
        short8 a[4];
        #pragma unroll
        for (int ks = 0; ks < 4; ++ks)
            a[ks] = pack8(&A[(size_t)ac * HID + ks * 32 + quad * 8]);
        floatx4 acc[8];
        #pragma unroll
        for (int nt = 0; nt < 8; ++nt) acc[nt] = (floatx4){0.f, 0.f, 0.f, 0.f};
        #pragma unroll
        for (int ks = 0; ks < 4; ++ks)
            #pragma unroll
            for (int nt = 0; nt < 8; ++nt) {
                short8 bv = *(const short8*)swzp(sW, nt * 16 + l15, ks * 64 + quad * 16);
                acc[nt] = __builtin_amdgcn_mfma_f32_16x16x32_bf16(a[ks], bv, acc[nt], 0, 0, 0);
            }
        #pragma unroll
        for (int rr = 0; rr < 4; ++rr) {
            int orow = n0 + w * 16 + quad * 4 + rr;
            union { u16 u[8]; short8 v; } o;
            #pragma unroll
            for (int nt = 0; nt < 8; ++nt) o.u[nt] = f2bf(acc[nt][rr]);
            if (orow < N_NODES)
                *(short8*)&out[(size_t)orow * HID + l15 * 8] = o.v;
        }
    }
}

// ---------------- Stage 2: pe FFN + LN (512 thr, zero barriers) ------------
// CSR=true: write new_edge bf16 coalesced. CSR=false: atomic scatter (fb).
template<bool CSR>
__launch_bounds__(512, 4)
__global__ void k_edge_pe(const int* __restrict__ eidx,
                          const u16* __restrict__ P1, const u16* __restrict__ P2,
                          const float* __restrict__ el,
                          const u16* __restrict__ W1T, const float* __restrict__ b1v,
                          const u16* __restrict__ W2T, const float* __restrict__ b2v,
                          const float* __restrict__ g, const float* __restrict__ be,
                          u16* __restrict__ newE,
                          float* __restrict__ seg, float* __restrict__ cnt) {
    __shared__ __align__(16) u16 sW1[128 * 128];   // W1c (k 256..383), swizzled
    __shared__ __align__(16) u16 sW2[128 * 128];   // W2, swizzled
    __shared__ __align__(16) u16 sH[8][16 * 64];   // per-wave split transpose
    const int t = threadIdx.x;
    const int lane = t & 63, w = t >> 6;
    const int l15 = lane & 15, quad = lane >> 4;

    for (int i = t; i < 2048; i += 512) {
        int n = i >> 4, q = i & 15;
        *(uint4*)swzp(sW1, n, q * 16) = *(const uint4*)&W1T[n * 384 + 256 + q * 8];
        *(uint4*)swzp(sW2, n, q * 16) = *(const uint4*)&W2T[n * 128 + q * 8];
    }
    float b1r[8], b2r[8], gr[8], ber[8];
    #pragma unroll
    for (int nt = 0; nt < 8; ++nt) {
        int col = nt * 16 + l15;
        b1r[nt] = b1v[col]; b2r[nt] = b2v[col]; gr[nt] = g[col]; ber[nt] = be[col];
    }
    __syncthreads();

    for (int tile = blockIdx.x; tile < N_EDGES / 128; tile += gridDim.x) {
        const int e0 = tile * 128;
        const int em = e0 + w * 16 + l15;          // A-frag / output row
        int snd[4], rcv[4];
        #pragma unroll
        for (int rr = 0; rr < 4; ++rr) {           // C rows
            int e = e0 + w * 16 + quad * 4 + rr;
            int2 p = *(const int2*)&eidx[e * 2];
            snd[rr] = p.x; rcv[rr] = p.y;
        }
        floatx4 acc[8];
        #pragma unroll
        for (int rr = 0; rr < 4; ++rr) {
            union { u16 u[8]; short8 v; } p1, p2;
            p1.v = *(const short8*)&P1[(size_t)snd[rr] * HID + l15 * 8];
            p2.v = *(const short8*)&P2[(size_t)rcv[rr] * HID + l15 * 8];
            #pragma unroll
            for (int nt = 0; nt < 8; ++nt)
                acc[nt][rr] = b1r[nt] + bf2f(p1.u[nt]) + bf2f(p2.u[nt]);
        }
        short8 a[4];
        #pragma unroll
        for (int ks = 0; ks < 4; ++ks)
            a[ks] = pack8(&el[(size_t)em * HID + ks * 32 + quad * 8]);
        #pragma unroll
        for (int ks = 0; ks < 4; ++ks)
            #pragma unroll
            for (int nt = 0; nt < 8; ++nt) {
                short8 bv = *(const short8*)swzp(sW1, nt * 16 + l15, ks * 64 + quad * 16);
                acc[nt] = __builtin_amdgcn_mfma_f32_16x16x32_bf16(a[ks], bv, acc[nt], 0, 0, 0);
            }
        // h = silu(acc) -> split transpose -> ha
        short8 ha[4];
        #pragma unroll
        for (int ph = 0; ph < 2; ++ph) {
            #pragma unroll
            for (int n4 = 0; n4 < 4; ++n4) {
                int nt = ph * 4 + n4;
                #pragma unroll
                for (int rr = 0; rr < 4; ++rr)
                    *(u16*)swz64(sH[w], quad * 4 + rr, (n4 * 16 + l15) * 2) =
                        f2bf(siluf(acc[nt][rr]));
            }
            #pragma unroll
            for (int k2 = 0; k2 < 2; ++k2)
                ha[ph * 2 + k2] = *(const short8*)swz64(sH[w], l15, k2 * 64 + quad * 16);
        }
        floatx4 acc2[8];
        #pragma unroll
        for (int nt = 0; nt < 8; ++nt) acc2[nt] = (floatx4){0.f, 0.f, 0.f, 0.f};
        #pragma unroll
        for (int ks = 0; ks < 4; ++ks)
            #pragma unroll
            for (int nt = 0; nt < 8; ++nt) {
                short8 bv = *(const short8*)swzp(sW2, nt * 16 + l15, ks * 64 + quad * 16);
                acc2[nt] = __builtin_amdgcn_mfma_f32_16x16x32_bf16(ha[ks], bv, acc2[nt], 0, 0, 0);
            }
        // LN
        float sum[4] = {0, 0, 0, 0}, sq[4] = {0, 0, 0, 0};
        #pragma unroll
        for (int nt = 0; nt < 8; ++nt)
            #pragma unroll
            for (int rr = 0; rr < 4; ++rr) {
                float v = acc2[nt][rr] + b2r[nt];
                acc2[nt][rr] = v; sum[rr] += v; sq[rr] += v * v;
            }
        #pragma unroll
        for (int m = 1; m < 16; m <<= 1)
            #pragma unroll
            for (int rr = 0; rr < 4; ++rr) {
                sum[rr] += __shfl_xor(sum[rr], m);
                sq[rr]  += __shfl_xor(sq[rr], m);
            }
        float mu[4], rs[4];
        #pragma unroll
        for (int rr = 0; rr < 4; ++rr) {
            mu[rr] = sum[rr] * (1.0f / HID);
            float var = fmaxf(sq[rr] * (1.0f / HID) - mu[rr] * mu[rr], 0.f);
            rs[rr] = rsqrtf(var + LN_EPS);
        }
        if (CSR) {
            // LN'd bf16 -> split transpose -> coalesced 16B row stores
            #pragma unroll
            for (int ph = 0; ph < 2; ++ph) {
                #pragma unroll
                for (int n4 = 0; n4 < 4; ++n4) {
                    int nt = ph * 4 + n4;
                    #pragma unroll
                    for (int rr = 0; rr < 4; ++rr)
                        *(u16*)swz64(sH[w], quad * 4 + rr, (n4 * 16 + l15) * 2) =
                            f2bf((acc2[nt][rr] - mu[rr]) * rs[rr] * gr[nt] + ber[nt]);
                }
                #pragma unroll
                for (int k2 = 0; k2 < 2; ++k2) {
                    short8 row = *(const short8*)swz64(sH[w], l15, k2 * 64 + quad * 16);
                    *(short8*)&newE[(size_t)em * HID + ph * 64 + k2 * 32 + quad * 8] = row;
                }
            }
        } else {
            #pragma unroll
            for (int nt = 0; nt < 8; ++nt) {
                int col = nt * 16 + l15;
                #pragma unroll
                for (int rr = 0; rr < 4; ++rr) {
                    float v = (acc2[nt][rr] - mu[rr]) * rs[rr] * gr[nt] + ber[nt];
                    atomicAdd(&seg[(size_t)rcv[rr] * HID + col], v);
                }
            }
            if (l15 == 0) {
                #pragma unroll
                for (int rr = 0; rr < 4; ++rr) atomicAdd(&cnt[rcv[rr]], 1.0f);
            }
        }
    }
}

// ---------------- mean over CSR edge lists ---------------------------------
__launch_bounds__(256)
__global__ void k_mean(const u16* __restrict__ newE, const int* __restrict__ offs,
                       const int* __restrict__ csr, u16* __restrict__ meanB) {
    const int wid = (int)((blockIdx.x * blockDim.x + threadIdx.x) >> 6);
    const int lane = threadIdx.x & 63;
    const int nW = (int)((gridDim.x * blockDim.x) >> 6);
    for (int n = wid; n < N_NODES; n += nW) {
        int s0 = offs[n], s1 = offs[n + 1];
        float a0 = 0.f, a1 = 0.f;
        for (int d = s0; d < s1; ++d) {
            int e = csr[d];
            unsigned int v = *(const unsigned int*)&newE[(size_t)e * HID + lane * 2];
            a0 += bf2f((u16)(v & 0xFFFFu));
            a1 += bf2f((u16)(v >> 16));
        }
        int deg = s1 - s0;
        float inv = 1.0f / (float)(deg > 0 ? deg : 1);
        unsigned int o = (unsigned int)f2bf(a0 * inv) | (((unsigned int)f2bf(a1 * inv)) << 16);
        *(unsigned int*)&meanB[(size_t)n * HID + lane * 2] = o;
    }
}

// ---------------- Stage 3: node FFNs (512 thr, zero barriers) --------------
template<bool CSR>
__launch_bounds__(512, 4)
__global__ void k_node(const u16* __restrict__ Q1, const u16* __restrict__ meanB,
                       const float* __restrict__ seg, const float* __restrict__ cnt,
                       const u16* __restrict__ W1T, const float* __restrict__ b1v,
                       const u16* __restrict__ W2T, const float* __restrict__ b2v,
                       const float* __restrict__ g, const float* __restrict__ be,
                       const u16* __restrict__ noW1T, const float* __restrict__ nob1,
                       const float* __restrict__ noW2, const float* __restrict__ nob2,
                       float* __restrict__ outN) {
    __shared__ __align__(16) u16 sW1[128 * 128];   // pnW1b (k 128..255), swizzled
    __shared__ __align__(16) u16 sW2[128 * 128];   // pnW2, swizzled
    __shared__ __align__(16) u16 sH[8][16 * 64];   // split transpose
    const int t = threadIdx.x;
    const int lane = t & 63, w = t >> 6;
    const int l15 = lane & 15, quad = lane >> 4;

    for (int i = t; i < 2048; i += 512) {
        int n = i >> 4, q = i & 15;
        *(uint4*)swzp(sW1, n, q * 16) = *(const uint4*)&W1T[n * 256 + 128 + q * 8];
        *(uint4*)swzp(sW2, n, q * 16) = *(const uint4*)&W2T[n * 128 + q * 8];
    }
    float b1r[8], b2r[8], gr[8], ber[8], nob1r[8], w2r[8][3];
    #pragma unroll
    for (int nt = 0; nt < 8; ++nt) {
        int col = nt * 16 + l15;
        b1r[nt] = b1v[col]; b2r[nt] = b2v[col]; gr[nt] = g[col]; ber[nt] = be[col];
        nob1r[nt] = nob1[col];
        #pragma unroll
        for (int c = 0; c < 3; ++c) w2r[nt][c] = noW2[col * 3 + c];
    }
    float nob2r[3] = {nob2[0], nob2[1], nob2[2]};
    __syncthreads();

    const int NT = (N_NODES + 127) / 128;
    for (int tile = blockIdx.x; tile < NT; tile += gridDim.x) {
        const int n0 = tile * 128;
        const int node = n0 + w * 16 + l15;        // A-frag row
        const int nc = node < N_NODES ? node : 0;
        short8 a[4];
        if (CSR) {
            #pragma unroll
            for (int ks = 0; ks < 4; ++ks)
                a[ks] = *(const short8*)&meanB[(size_t)nc * HID + ks * 32 + quad * 8];
        } else {
            float inv = 1.0f / fmaxf(cnt[nc], 1.0f);
            #pragma unroll
            for (int ks = 0; ks < 4; ++ks)
                a[ks] = pack8s(&seg[(size_t)nc * HID + ks * 32 + quad * 8], inv);
        }
        floatx4 acc[8];
        int crow[4];
        #pragma unroll
        for (int rr = 0; rr < 4; ++rr) {
            int r = n0 + w * 16 + quad * 4 + rr;
            crow[rr] = r;
            r = r < N_NODES ? r : 0;
            union { u16 u[8]; short8 v; } q1;
            q1.v = *(const short8*)&Q1[(size_t)r * HID + l15 * 8];   // permuted
            #pragma unroll
            for (int nt = 0; nt < 8; ++nt)
                acc[nt][rr] = b1r[nt] + bf2f(q1.u[nt]);
        }
        #pragma unroll
        for (int ks = 0; ks < 4; ++ks)
            #pragma unroll
            for (int nt = 0; nt < 8; ++nt) {
                short8 bv = *(const short8*)swzp(sW1, nt * 16 + l15, ks * 64 + quad * 16);
                acc[nt] = __builtin_amdgcn_mfma_f32_16x16x32_bf16(a[ks], bv, acc[nt], 0, 0, 0);
            }
        // silu -> split transpose
        short8 ha[4];
        #pragma unroll
        for (int ph = 0; ph < 2; ++ph) {
            #pragma unroll
            for (int n4 = 0; n4 < 4; ++n4) {
                int nt = ph * 4 + n4;
                #pragma unroll
                for (int rr = 0; rr < 4; ++rr)
                    *(u16*)swz64(sH[w], quad * 4 + rr, (n4 * 16 + l15) * 2) =
                        f2bf(siluf(acc[nt][rr]));
            }
            #pragma unroll
            for (int k2 = 0; k2 < 2; ++k2)
                ha[ph * 2 + k2] = *(const short8*)swz64(sH[w], l15, k2 * 64 + quad * 16);
        }
        floatx4 acc2[8];
        #pragma unroll
        for (int nt = 0; nt < 8; ++nt) acc2[nt] = (floatx4){0.f, 0.f, 0.f, 0.f};
        #pragma unroll
        for (int ks = 0; ks < 4; ++ks)
            #pragma unroll
            for (int nt = 0; nt < 8; ++nt) {
                short8 bv = *(const short8*)swzp(sW2, nt * 16 + l15, ks * 64 + quad * 16);
                acc2[nt] = __builtin_amdgcn_mfma_f32_16x16x32_bf16(ha[ks], bv, acc2[nt], 0, 0, 0);
            }
        // LN -> new_node bf16 -> split transpose -> h2
        float sum[4] = {0, 0, 0, 0}, sq[4] = {0, 0, 0, 0};
        #pragma unroll
        for (int nt = 0; nt < 8; ++nt)
            #pragma unroll
            for (int rr = 0; rr < 4; ++rr) {
                float v = acc2[nt][rr] + b2r[nt];
                acc2[nt][rr] = v; sum[rr] += v; sq[rr] += v * v;
            }
        #pragma unroll
        for (int m = 1; m < 16; m <<= 1)
            #pragma unroll
            for (int rr = 0; rr < 4; ++rr) {
                sum[rr] += __shfl_xor(sum[rr], m);
                sq[rr]  += __shfl_xor(sq[rr], m);
            }
        float mu[4], rs[4];
        #pragma unroll
        for (int rr = 0; rr < 4; ++rr) {
            mu[rr] = sum[rr] * (1.0f / HID);
            float var = fmaxf(sq[rr] * (1.0f / HID) - mu[rr] * mu[rr], 0.f);
            rs[rr] = rsqrtf(var + LN_EPS);
        }
        short8 h2[4];
        #pragma unroll
        for (int ph = 0; ph < 2; ++ph) {
            #pragma unroll
            for (int n4 = 0; n4 < 4; ++n4) {
                int nt = ph * 4 + n4;
                #pragma unroll
                for (int rr = 0; rr < 4; ++rr)
                    *(u16*)swz64(sH[w], quad * 4 + rr, (n4 * 16 + l15) * 2) =
                        f2bf((acc2[nt][rr] - mu[rr]) * rs[rr] * gr[nt] + ber[nt]);
            }
            #pragma unroll
            for (int k2 = 0; k2 < 2; ++k2)
                h2[ph * 2 + k2] = *(const short8*)swz64(sH[w], l15, k2 * 64 + quad * 16);
        }
        floatx4 acc3[8];
        #pragma unroll
        for (int nt = 0; nt < 8; ++nt) acc3[nt] = (floatx4){0.f, 0.f, 0.f, 0.f};
        #pragma unroll
        for (int ks = 0; ks < 4; ++ks)
            #pragma unroll
            for (int nt = 0; nt < 8; ++nt) {   // noW1 B-frags from global (L1-resident)
                short8 bv = *(const short8*)&noW1T[(size_t)(nt * 16 + l15) * 128 +
                                                   ks * 32 + quad * 8];
                acc3[nt] = __builtin_amdgcn_mfma_f32_16x16x32_bf16(h2[ks], bv, acc3[nt], 0, 0, 0);
            }
        float p[4][3] = {{0,0,0},{0,0,0},{0,0,0},{0,0,0}};
        #pragma unroll
        for (int nt = 0; nt < 8; ++nt)
            #pragma unroll
            for (int rr = 0; rr < 4; ++rr) {
                float h3 = sigmf(acc3[nt][rr] + nob1r[nt]);
                #pragma unroll
                for (int c = 0; c < 3; ++c) p[rr][c] += h3 * w2r[nt][c];
            }
        #pragma unroll
        for (int m = 1; m < 16; m <<= 1)
            #pragma unroll
            for (int rr = 0; rr < 4; ++rr)
                #pragma unroll
                for (int c = 0; c < 3; ++c) p[rr][c] += __shfl_xor(p[rr][c], m);
        if (l15 < 3) {
            #pragma unroll
            for (int rr = 0; rr < 4; ++rr)
                if (crow[rr] < N_NODES)
                    outN[(size_t)crow[rr] * 3 + l15] = p[rr][l15] + nob2r[l15];
        }
    }
}

extern "C" void kernel_launch(void* const* d_in, const int* in_sizes, int n_in,
                              void* d_out, int out_size, void* d_ws, size_t ws_size,
                              hipStream_t stream) {
    const int*   eidx  = (const int*)d_in[0];
    const float* ef    = (const float*)d_in[1];
    const float* nlat  = (const float*)d_in[2];
    const float* nfeat = (const float*)d_in[3];
    const float* eeW1 = (const float*)d_in[4];
    const float* eeb1 = (const float*)d_in[5];
    const float* eeW2 = (const float*)d_in[6];
    const float* eeb2 = (const float*)d_in[7];
    const float* eeg  = (const float*)d_in[8];
    const float* eebe = (const float*)d_in[9];
    const float* peW1 = (const float*)d_in[10];
    const float* peb1 = (const float*)d_in[11];
    const float* peW2 = (const float*)d_in[12];
    const float* peb2 = (const float*)d_in[13];
    const float* peg  = (const float*)d_in[14];
    const float* pebe = (const float*)d_in[15];
    const float* pnW1 = (const float*)d_in[16];
    const float* pnb1 = (const float*)d_in[17];
    const float* pnW2 = (const float*)d_in[18];
    const float* pnb2 = (const float*)d_in[19];
    const float* png_ = (const float*)d_in[20];
    const float* pnbe = (const float*)d_in[21];
    const float* noW1 = (const float*)d_in[22];
    const float* nob1 = (const float*)d_in[23];
    const float* noW2 = (const float*)d_in[24];
    const float* nob2 = (const float*)d_in[25];

    float* outEL = (float*)d_out;
    float* outN  = outEL + (size_t)N_EDGES * HID;
    char* ws = (char*)d_ws;

    const size_t WS_CSR = 130494928;
    const bool useCSR = ws_size >= WS_CSR;

    u16 *eeW2T, *peW1T, *peW2T, *pnW1T, *pnW2T, *noW1T, *P1, *P2;
    if (useCSR) {
        eeW2T = (u16*)(ws + 0);            // 32,768
        peW1T = (u16*)(ws + 32768);        // 98,304
        peW2T = (u16*)(ws + 131072);       // 32,768
        pnW1T = (u16*)(ws + 163840);       // 65,536
        pnW2T = (u16*)(ws + 229376);       // 32,768
        noW1T = (u16*)(ws + 262144);       // 32,768
        int* icnt = (int*)(ws + 294912);   // 200,000
        int* offs = (int*)(ws + 494912);   // 200,004
        int* fpos = (int*)(ws + 694916);   // 200,000
        int* csr  = (int*)(ws + 894916);   // 1,600,000 -> 2,494,916 (pad to 2,494,928)
        P1 = (u16*)(ws + 2494928);         // 12,800,000 (also Q1)
        P2 = (u16*)(ws + 15294928);        // 12,800,000 (also meanB)
        u16* newE  = (u16*)(ws + 28094928);    // 102,400,000 -> 130,494,928
        u16* meanB = P2;                        // alias: P2 dead after pe

        hipMemsetAsync(ws + 294912, 0, 600004, stream);   // icnt+offs+fpos

        k_prepT<<<64, 256, 0, stream>>>(eeW2, eeW2T, 128, 128);
        k_prepT<<<192, 256, 0, stream>>>(peW1, peW1T, 384, 128);
        k_prepT<<<64, 256, 0, stream>>>(peW2, peW2T, 128, 128);
        k_prepT<<<128, 256, 0, stream>>>(pnW1, pnW1T, 256, 128);
        k_prepT<<<64, 256, 0, stream>>>(pnW2, pnW2T, 128, 128);
        k_prepT<<<64, 256, 0, stream>>>(noW1, noW1T, 128, 128);

        k_hist<<<782, 512, 0, stream>>>(eidx, icnt);
        k_scan<<<1, 1024, 0, stream>>>(icnt, offs);
        k_fill<<<782, 512, 0, stream>>>(eidx, offs, fpos, csr);

        k_edge_ee<<<1024, 256, 0, stream>>>(ef, eeW1, eeb1, eeW2T, eeb2, eeg, eebe, outEL);
        k_gemm128<<<512, 256, 0, stream>>>(nlat,  peW1T, 384, 0,   P1);
        k_gemm128<<<512, 256, 0, stream>>>(nfeat, peW1T, 384, 128, P2);
        k_edge_pe<true><<<512, 512, 0, stream>>>(eidx, P1, P2, outEL, peW1T, peb1,
                                                 peW2T, peb2, peg, pebe, newE,
                                                 (float*)nullptr, (float*)nullptr);
        k_mean<<<1024, 256, 0, stream>>>(newE, offs, csr, meanB);
        k_gemm128<<<512, 256, 0, stream>>>(nfeat, pnW1T, 256, 0, P1);   // Q1
        k_node<true><<<391, 512, 0, stream>>>(P1, meanB, (float*)nullptr, (float*)nullptr,
                                              pnW1T, pnb1, pnW2T, pnb2, png_, pnbe,
                                              noW1T, nob1, noW2, nob2, outN);
    } else {
        // round-6 proven layout (51,694,912 B)
        float* seg = (float*)ws;                   // 25,600,000
        float* cnt = (float*)(ws + 25600000);      //    200,000
        eeW2T = (u16*)(ws + 25800000);
        peW1T = (u16*)(ws + 25832768);
        peW2T = (u16*)(ws + 25931072);
        pnW1T = (u16*)(ws + 25963840);
        pnW2T = (u16*)(ws + 26029376);
        noW1T = (u16*)(ws + 26062144);
        P1    = (u16*)(ws + 26094912);
        P2    = (u16*)(ws + 38894912);

        hipMemsetAsync(ws, 0, 25800000, stream);

        k_prepT<<<64, 256, 0, stream>>>(eeW2, eeW2T, 128, 128);
        k_prepT<<<192, 256, 0, stream>>>(peW1, peW1T, 384, 128);
        k_prepT<<<64, 256, 0, stream>>>(peW2, peW2T, 128, 128);
        k_prepT<<<128, 256, 0, stream>>>(pnW1, pnW1T, 256, 128);
        k_prepT<<<64, 256, 0, stream>>>(pnW2, pnW2T, 128, 128);
        k_prepT<<<64, 256, 0, stream>>>(noW1, noW1T, 128, 128);

        k_edge_ee<<<1024, 256, 0, stream>>>(ef, eeW1, eeb1, eeW2T, eeb2, eeg, eebe, outEL);
        k_gemm128<<<512, 256, 0, stream>>>(nlat,  peW1T, 384, 0,   P1);
        k_gemm128<<<512, 256, 0, stream>>>(nfeat, peW1T, 384, 128, P2);
        k_edge_pe<false><<<512, 512, 0, stream>>>(eidx, P1, P2, outEL, peW1T, peb1,
                                                  peW2T, peb2, peg, pebe, (u16*)nullptr,
                                                  seg, cnt);
        k_gemm128<<<512, 256, 0, stream>>>(nfeat, pnW1T, 256, 0, P1);   // Q1
        k_node<false><<<391, 512, 0, stream>>>(P1, (u16*)nullptr, seg, cnt,
                                               pnW1T, pnb1, pnW2T, pnb2, png_, pnbe,
                                               noW1T, nob1, noW2, nob2, outN);
    }
}

// Round 5
// 1030.316 us; speedup vs baseline: 1.0119x; 1.0119x over previous
//
#include <hip/hip_runtime.h>

// ---------------------------------------------------------------------------
// Round 9: atomic-free aggregation WITHOUT materializing new_edge.
//  Evidence: r6->r7 occupancy 2x -> pe flat (atomic pipe saturated ~230G/s);
//  r8 CSR+newE(102MB)+k_mean -> FETCH 715MB, wall 1043 (traffic-bound).
//  Design: sort edges by receiver (CSR). One WAVE per node: compute its
//  edges' pe-FFN+LN in 16-row MFMA tiles (proven frag/transpose/LN code),
//  mask padded rows, column-sum in-register (shfl x2), write one 256B bf16
//  mean row. No atomics, no seg, no newE, no k_mean. node reads meanB.
//  All large ws arrays 256B-aligned (r8's newE was misaligned -> RMW blowup).
//  ws need = 42.5MB < 51.7MB (proven present in r6).
// ---------------------------------------------------------------------------

#define N_NODES 50000
#define N_EDGES 400000
#define HID 128
#define LN_EPS 1e-5f

typedef unsigned short u16;
typedef __attribute__((ext_vector_type(8))) short short8;   // 8 x bf16
typedef __attribute__((ext_vector_type(4))) float floatx4;  // MFMA C/D

__device__ __forceinline__ u16 f2bf(float f) {
    union { float f; unsigned int i; } v; v.f = f;
    unsigned int x = v.i;
    return (u16)((x + 0x7FFFu + ((x >> 16) & 1u)) >> 16);  // RNE
}
__device__ __forceinline__ float bf2f(u16 u) {
    union { unsigned int i; float f; } v; v.i = ((unsigned int)u) << 16;
    return v.f;
}
__device__ __forceinline__ float siluf(float x) { return x * (1.0f / (1.0f + __expf(-x))); }
__device__ __forceinline__ float sigmf(float x) { return 1.0f / (1.0f + __expf(-x)); }

__device__ __forceinline__ short8 pack8(const float* __restrict__ p) {
    union { u16 u[8]; short8 v; } o;
    float4 a = *(const float4*)p;
    float4 b = *(const float4*)(p + 4);
    o.u[0] = f2bf(a.x); o.u[1] = f2bf(a.y); o.u[2] = f2bf(a.z); o.u[3] = f2bf(a.w);
    o.u[4] = f2bf(b.x); o.u[5] = f2bf(b.y); o.u[6] = f2bf(b.z); o.u[7] = f2bf(b.w);
    return o.v;
}

// 256B-row LDS, 16B chunks XOR-swizzled by row
__device__ __forceinline__ char* swzp(const void* base, int row, int b) {
    return (char*)base + row * 256 + ((b & 15) | ((((b >> 4) ^ row) & 15) << 4));
}
// 128B-row LDS (64-col bf16), 16B chunks XOR-swizzled by row
__device__ __forceinline__ char* swz64(const void* base, int row, int b) {
    return (char*)base + row * 128 + ((b & 15) | ((((b >> 4) ^ row) & 7) << 4));
}

// W fp32 (K x N) row-major -> WT bf16 (N x K) row-major
__global__ void k_prepT(const float* __restrict__ src, u16* __restrict__ dst, int K, int N) {
    int i = blockIdx.x * blockDim.x + threadIdx.x;
    if (i < K * N) {
        int k = i / N, n = i - k * N;
        dst[n * K + k] = f2bf(src[i]);
    }
}

// ---------------- CSR build ------------------------------------------------
__global__ void k_hist(const int* __restrict__ eidx, int* __restrict__ icnt) {
    int e = blockIdx.x * blockDim.x + threadIdx.x;
    if (e < N_EDGES) atomicAdd(&icnt[eidx[e * 2 + 1]], 1);
}

__launch_bounds__(1024)
__global__ void k_scan(const int* __restrict__ icnt, int* __restrict__ offs) {
    __shared__ int s[1024];
    const int t = threadIdx.x;
    const int CH = 49;                       // 1024*49 >= 50000
    int base = t * CH;
    int sum = 0;
    for (int j = 0; j < CH; ++j) {
        int i = base + j;
        if (i < N_NODES) sum += icnt[i];
    }
    s[t] = sum;
    __syncthreads();
    for (int off = 1; off < 1024; off <<= 1) {
        int v = (t >= off) ? s[t - off] : 0;
        __syncthreads();
        s[t] += v;
        __syncthreads();
    }
    int run = s[t] - sum;                    // exclusive prefix of chunk
    for (int j = 0; j < CH; ++j) {
        int i = base + j;
        if (i < N_NODES) { offs[i] = run; run += icnt[i]; }
    }
    if (t == 1023) offs[N_NODES] = s[1023];
}

// csrES[d] = (edge_index, sender) for receiver-sorted edge slots
__global__ void k_fill(const int* __restrict__ eidx, const int* __restrict__ offs,
                       int* __restrict__ fpos, int2* __restrict__ csrES) {
    int e = blockIdx.x * blockDim.x + threadIdx.x;
    if (e < N_EDGES) {
        int2 pr = *(const int2*)&eidx[e * 2];      // x=snd, y=rcv
        int p = atomicAdd(&fpos[pr.y], 1);
        int2 es; es.x = e; es.y = pr.x;
        csrES[offs[pr.y] + p] = es;
    }
}

// ---------------- Stage 1: ee FFN + LN -> edge_lat (round-6 proven) --------
__launch_bounds__(256)
__global__ void k_edge_ee(const float* __restrict__ ef,
                          const float* __restrict__ W1, const float* __restrict__ b1v,
                          const u16* __restrict__ W2T, const float* __restrict__ b2v,
                          const float* __restrict__ g, const float* __restrict__ be,
                          float* __restrict__ outEL) {
    __shared__ __align__(16) u16 sW2[128 * 136];
    __shared__ float sW1[384];
    __shared__ float sB1[128];
    const int t = threadIdx.x;
    const int lane = t & 63, w = t >> 6;
    const int l15 = lane & 15, quad = lane >> 4;

    for (int i = t; i < 2048; i += 256) {
        int n = i >> 4, q = i & 15;
        *(uint4*)&sW2[n * 136 + q * 8] = *(const uint4*)&W2T[n * 128 + q * 8];
    }
    for (int i = t; i < 384; i += 256) sW1[i] = W1[i];
    if (t < 128) sB1[t] = b1v[t];
    __syncthreads();

    float b2r[8], gr[8], ber[8];
    #pragma unroll
    for (int nt = 0; nt < 8; ++nt) {
        int col = nt * 16 + l15;
        b2r[nt] = b2v[col]; gr[nt] = g[col]; ber[nt] = be[col];
    }

    for (int tile = blockIdx.x; tile < N_EDGES / 64; tile += gridDim.x) {
        const int e0 = tile * 64;
        const int em = e0 + w * 16 + l15;
        float f0 = ef[em * 3 + 0], f1 = ef[em * 3 + 1], f2 = ef[em * 3 + 2];
        short8 ha[4];
        #pragma unroll
        for (int ks = 0; ks < 4; ++ks) {
            union { u16 u[8]; short8 v; } hh;
            #pragma unroll
            for (int jj = 0; jj < 8; ++jj) {
                int j = ks * 32 + quad * 8 + jj;
                float x = sB1[j] + f0 * sW1[j] + f1 * sW1[128 + j] + f2 * sW1[256 + j];
                hh.u[jj] = f2bf(siluf(x));
            }
            ha[ks] = hh.v;
        }
        floatx4 acc[8];
        #pragma unroll
        for (int nt = 0; nt < 8; ++nt) acc[nt] = (floatx4){0.f, 0.f, 0.f, 0.f};
        #pragma unroll
        for (int ks = 0; ks < 4; ++ks) {
            #pragma unroll
            for (int nt = 0; nt < 8; ++nt) {
                short8 bv = *(const short8*)&sW2[(nt * 16 + l15) * 136 + ks * 32 + quad * 8];
                acc[nt] = __builtin_amdgcn_mfma_f32_16x16x32_bf16(ha[ks], bv, acc[nt], 0, 0, 0);
            }
        }
        float sum[4] = {0, 0, 0, 0}, sq[4] = {0, 0, 0, 0};
        #pragma unroll
        for (int nt = 0; nt < 8; ++nt)
            #pragma unroll
            for (int rr = 0; rr < 4; ++rr) {
                float v = acc[nt][rr] + b2r[nt];
                acc[nt][rr] = v; sum[rr] += v; sq[rr] += v * v;
            }
        #pragma unroll
        for (int m = 1; m < 16; m <<= 1)
            #pragma unroll
            for (int rr = 0; rr < 4; ++rr) {
                sum[rr] += __shfl_xor(sum[rr], m);
                sq[rr]  += __shfl_xor(sq[rr], m);
            }
        float mu[4], rs[4];
        #pragma unroll
        for (int rr = 0; rr < 4; ++rr) {
            mu[rr] = sum[rr] * (1.0f / HID);
            float var = fmaxf(sq[rr] * (1.0f / HID) - mu[rr] * mu[rr], 0.f);
            rs[rr] = rsqrtf(var + LN_EPS);
        }
        #pragma unroll
        for (int nt = 0; nt < 8; ++nt) {
            int col = nt * 16 + l15;
            #pragma unroll
            for (int rr = 0; rr < 4; ++rr) {
                int row = e0 + w * 16 + quad * 4 + rr;
                outEL[(size_t)row * HID + col] = (acc[nt][rr] - mu[rr]) * rs[rr] * gr[nt] + ber[nt];
            }
        }
    }
}

// ---------------- Dense helper: out = bf16(A @ W), PERMUTED row layout -----
// out[row][l15*8 + nt] = (A@W)[row][nt*16 + l15]   (proven round 7)
__launch_bounds__(256)
__global__ void k_gemm128(const float* __restrict__ A, const u16* __restrict__ WT,
                          int ldw, int koff, u16* __restrict__ out) {
    __shared__ __align__(16) u16 sW[128 * 128];
    const int t = threadIdx.x;
    const int lane = t & 63, w = t >> 6;
    const int l15 = lane & 15, quad = lane >> 4;
    for (int i = t; i < 2048; i += 256) {
        int n = i >> 4, q = i & 15;
        *(uint4*)swzp(sW, n, q * 16) = *(const uint4*)&WT[n * ldw + koff + q * 8];
    }
    __syncthreads();
    const int NT = (N_NODES + 63) / 64;
    for (int tile = blockIdx.x; tile < NT; tile += gridDim.x) {
        const int n0 = tile * 64;
        const int arow = n0 + w * 16 + l15;
        const int ac = arow < N_NODES ? arow : 0;
        short8 a[4];
        #pragma unroll
        for (int ks = 0; ks < 4; ++ks)
            a[ks] = pack8(&A[(size_t)ac * HID + ks * 32 + quad * 8]);
        floatx4 acc[8];
        #pragma unroll
        for (int nt = 0; nt < 8; ++nt) acc[nt] = (floatx4){0.f, 0.f, 0.f, 0.f};
        #pragma unroll
        for (int ks = 0; ks < 4; ++ks)
            #pragma unroll
            for (int nt = 0; nt < 8; ++nt) {
                short8 bv = *(const short8*)swzp(sW, nt * 16 + l15, ks * 64 + quad * 16);
                acc[nt] = __builtin_amdgcn_mfma_f32_16x16x32_bf16(a[ks], bv, acc[nt], 0, 0, 0);
            }
        #pragma unroll
        for (int rr = 0; rr < 4; ++rr) {
            int orow = n0 + w * 16 + quad * 4 + rr;
            union { u16 u[8]; short8 v; } o;
            #pragma unroll
            for (int nt = 0; nt < 8; ++nt) o.u[nt] = f2bf(acc[nt][rr]);
            if (orow < N_NODES)
                *(short8*)&out[(size_t)orow * HID + l15 * 8] = o.v;
        }
    }
}

// ---------------- Stage 2: per-NODE pe FFN + LN + in-register mean ---------
// One wave per node. For each 16-edge chunk of the node's CSR list:
//   acc = b1 + P1[snd] + P2[n];  acc += el[e] @ W1c (K=128, LDS-resident)
//   h = silu(acc); y = h @ W2 + b2; LN per edge-row; masked column-sum.
// mean = colsum / deg -> meanB[n] (bf16, 256B row). ZERO atomics.
__launch_bounds__(256)
__global__ void k_pe_node(const int2* __restrict__ csrES, const int* __restrict__ offs,
                          const u16* __restrict__ P1, const u16* __restrict__ P2,
                          const float* __restrict__ el,
                          const u16* __restrict__ W1T, const float* __restrict__ b1v,
                          const u16* __restrict__ W2T, const float* __restrict__ b2v,
                          const float* __restrict__ g, const float* __restrict__ be,
                          u16* __restrict__ meanB) {
    __shared__ __align__(16) u16 sW1[128 * 128];   // peW1c (k 256..383), swizzled
    __shared__ __align__(16) u16 sW2[128 * 128];   // peW2, swizzled
    __shared__ __align__(16) u16 sH[4][16 * 64];   // per-wave split transpose / mean stage
    const int t = threadIdx.x;
    const int lane = t & 63, w = t >> 6;           // 4 waves
    const int l15 = lane & 15, quad = lane >> 4;

    for (int i = t; i < 2048; i += 256) {
        int n = i >> 4, q = i & 15;
        *(uint4*)swzp(sW1, n, q * 16) = *(const uint4*)&W1T[n * 384 + 256 + q * 8];
        *(uint4*)swzp(sW2, n, q * 16) = *(const uint4*)&W2T[n * 128 + q * 8];
    }
    float b1r[8], b2r[8], gr[8], ber[8];
    #pragma unroll
    for (int nt = 0; nt < 8; ++nt) {
        int col = nt * 16 + l15;
        b1r[nt] = b1v[col]; b2r[nt] = b2v[col]; gr[nt] = g[col]; ber[nt] = be[col];
    }
    __syncthreads();

    const int nW = (int)((gridDim.x * blockDim.x) >> 6);
    const int wid = (int)((blockIdx.x * blockDim.x + threadIdx.x) >> 6);

    for (int n = wid; n < N_NODES; n += nW) {
        const int s0 = offs[n], s1 = offs[n + 1];
        const int deg = s1 - s0;
        float msum[8];
        #pragma unroll
        for (int nt = 0; nt < 8; ++nt) msum[nt] = 0.f;
        union { u16 u[8]; short8 v; } p2r;
        p2r.v = *(const short8*)&P2[(size_t)n * HID + l15 * 8];   // permuted row

        for (int c0 = s0; c0 < s1; c0 += 16) {
            int nv = s1 - c0; if (nv > 16) nv = 16;
            // (edge, snd) for this lane's A-row (clamped duplicate if padded)
            int2 es = csrES[c0 + (l15 < nv ? l15 : nv - 1)];
            // A-frags from el[e]
            short8 a[4];
            #pragma unroll
            for (int ks = 0; ks < 4; ++ks)
                a[ks] = pack8(&el[(size_t)es.x * HID + ks * 32 + quad * 8]);
            // acc = b1 + P1[snd(row)] + P2[n]  (C rows = quad*4+rr)
            floatx4 acc[8];
            #pragma unroll
            for (int rr = 0; rr < 4; ++rr) {
                int sndr = __shfl(es.y, quad * 4 + rr);
                union { u16 u[8]; short8 v; } p1r;
                p1r.v = *(const short8*)&P1[(size_t)sndr * HID + l15 * 8];
                #pragma unroll
                for (int nt = 0; nt < 8; ++nt)
                    acc[nt][rr] = b1r[nt] + bf2f(p1r.u[nt]) + bf2f(p2r.u[nt]);
            }
            #pragma unroll
            for (int ks = 0; ks < 4; ++ks)
                #pragma unroll
                for (int nt = 0; nt < 8; ++nt) {
                    short8 bv = *(const short8*)swzp(sW1, nt * 16 + l15, ks * 64 + quad * 16);
                    acc[nt] = __builtin_amdgcn_mfma_f32_16x16x32_bf16(a[ks], bv, acc[nt], 0, 0, 0);
                }
            // h = silu(acc) -> split transpose -> ha (wave-private)
            short8 ha[4];
            #pragma unroll
            for (int ph = 0; ph < 2; ++ph) {
                #pragma unroll
                for (int n4 = 0; n4 < 4; ++n4) {
                    int nt = ph * 4 + n4;
                    #pragma unroll
                    for (int rr = 0; rr < 4; ++rr)
                        *(u16*)swz64(sH[w], quad * 4 + rr, (n4 * 16 + l15) * 2) =
                            f2bf(siluf(acc[nt][rr]));
                }
                #pragma unroll
                for (int k2 = 0; k2 < 2; ++k2)
                    ha[ph * 2 + k2] = *(const short8*)swz64(sH[w], l15, k2 * 64 + quad * 16);
            }
            floatx4 acc2[8];
            #pragma unroll
            for (int nt = 0; nt < 8; ++nt) acc2[nt] = (floatx4){0.f, 0.f, 0.f, 0.f};
            #pragma unroll
            for (int ks = 0; ks < 4; ++ks)
                #pragma unroll
                for (int nt = 0; nt < 8; ++nt) {
                    short8 bv = *(const short8*)swzp(sW2, nt * 16 + l15, ks * 64 + quad * 16);
                    acc2[nt] = __builtin_amdgcn_mfma_f32_16x16x32_bf16(ha[ks], bv, acc2[nt], 0, 0, 0);
                }
            // + b2, LN per edge-row
            float sum[4] = {0, 0, 0, 0}, sq[4] = {0, 0, 0, 0};
            #pragma unroll
            for (int nt = 0; nt < 8; ++nt)
                #pragma unroll
                for (int rr = 0; rr < 4; ++rr) {
                    float v = acc2[nt][rr] + b2r[nt];
                    acc2[nt][rr] = v; sum[rr] += v; sq[rr] += v * v;
                }
            #pragma unroll
            for (int m = 1; m < 16; m <<= 1)
                #pragma unroll
                for (int rr = 0; rr < 4; ++rr) {
                    sum[rr] += __shfl_xor(sum[rr], m);
                    sq[rr]  += __shfl_xor(sq[rr], m);
                }
            float mu[4], rs[4];
            #pragma unroll
            for (int rr = 0; rr < 4; ++rr) {
                mu[rr] = sum[rr] * (1.0f / HID);
                float var = fmaxf(sq[rr] * (1.0f / HID) - mu[rr] * mu[rr], 0.f);
                rs[rr] = rsqrtf(var + LN_EPS);
            }
            // masked column accumulate (rows quad*4+rr < nv), reduce over quads
            #pragma unroll
            for (int nt = 0; nt < 8; ++nt) {
                float s = 0.f;
                #pragma unroll
                for (int rr = 0; rr < 4; ++rr) {
                    float v = (acc2[nt][rr] - mu[rr]) * rs[rr] * gr[nt] + ber[nt];
                    if (quad * 4 + rr < nv) s += v;
                }
                s += __shfl_xor(s, 16);
                s += __shfl_xor(s, 32);
                msum[nt] += s;
            }
        }
        // mean -> bf16 row via LDS lane-transpose (wave-internal ordering)
        float inv = 1.0f / (float)(deg > 0 ? deg : 1);
        u16* sm = (u16*)sH[w];
        if (quad == 0) {
            #pragma unroll
            for (int nt = 0; nt < 8; ++nt) sm[nt * 16 + l15] = f2bf(msum[nt] * inv);
        }
        if (quad == 0)
            *(short8*)&meanB[(size_t)n * HID + l15 * 8] = *(const short8*)&sm[l15 * 8];
    }
}

// ---------------- Stage 3: node FFNs (512 thr, zero barriers) --------------
__launch_bounds__(512, 4)
__global__ void k_node(const u16* __restrict__ Q1, const u16* __restrict__ meanB,
                       const u16* __restrict__ W1T, const float* __restrict__ b1v,
                       const u16* __restrict__ W2T, const float* __restrict__ b2v,
                       const float* __restrict__ g, const float* __restrict__ be,
                       const u16* __restrict__ noW1T, const float* __restrict__ nob1,
                       const float* __restrict__ noW2, const float* __restrict__ nob2,
                       float* __restrict__ outN) {
    __shared__ __align__(16) u16 sW1[128 * 128];   // pnW1b (k 128..255), swizzled
    __shared__ __align__(16) u16 sW2[128 * 128];   // pnW2, swizzled
    __shared__ __align__(16) u16 sH[8][16 * 64];   // split transpose
    const int t = threadIdx.x;
    const int lane = t & 63, w = t >> 6;
    const int l15 = lane & 15, quad = lane >> 4;

    for (int i = t; i < 2048; i += 512) {
        int n = i >> 4, q = i & 15;
        *(uint4*)swzp(sW1, n, q * 16) = *(const uint4*)&W1T[n * 256 + 128 + q * 8];
        *(uint4*)swzp(sW2, n, q * 16) = *(const uint4*)&W2T[n * 128 + q * 8];
    }
    float b1r[8], b2r[8], gr[8], ber[8], nob1r[8], w2r[8][3];
    #pragma unroll
    for (int nt = 0; nt < 8; ++nt) {
        int col = nt * 16 + l15;
        b1r[nt] = b1v[col]; b2r[nt] = b2v[col]; gr[nt] = g[col]; ber[nt] = be[col];
        nob1r[nt] = nob1[col];
        #pragma unroll
        for (int c = 0; c < 3; ++c) w2r[nt][c] = noW2[col * 3 + c];
    }
    float nob2r[3] = {nob2[0], nob2[1], nob2[2]};
    __syncthreads();

    const int NT = (N_NODES + 127) / 128;
    for (int tile = blockIdx.x; tile < NT; tile += gridDim.x) {
        const int n0 = tile * 128;
        const int node = n0 + w * 16 + l15;        // A-frag row
        const int nc = node < N_NODES ? node : 0;
        short8 a[4];
        #pragma unroll
        for (int ks = 0; ks < 4; ++ks)
            a[ks] = *(const short8*)&meanB[(size_t)nc * HID + ks * 32 + quad * 8];
        floatx4 acc[8];
        int crow[4];
        #pragma unroll
        for (int rr = 0; rr < 4; ++rr) {
            int r = n0 + w * 16 + quad * 4 + rr;
            crow[rr] = r;
            r = r < N_NODES ? r : 0;
            union { u16 u[8]; short8 v; } q1;
            q1.v = *(const short8*)&Q1[(size_t)r * HID + l15 * 8];   // permuted
            #pragma unroll
            for (int nt = 0; nt < 8; ++nt)
                acc[nt][rr] = b1r[nt] + bf2f(q1.u[nt]);
        }
        #pragma unroll
        for (int ks = 0; ks < 4; ++ks)
            #pragma unroll
            for (int nt = 0; nt < 8; ++nt) {
                short8 bv = *(const short8*)swzp(sW1, nt * 16 + l15, ks * 64 + quad * 16);
                acc[nt] = __builtin_amdgcn_mfma_f32_16x16x32_bf16(a[ks], bv, acc[nt], 0, 0, 0);
            }
        // silu -> split transpose
        short8 ha[4];
        #pragma unroll
        for (int ph = 0; ph < 2; ++ph) {
            #pragma unroll
            for (int n4 = 0; n4 < 4; ++n4) {
                int nt = ph * 4 + n4;
                #pragma unroll
                for (int rr = 0; rr < 4; ++rr)
                    *(u16*)swz64(sH[w], quad * 4 + rr, (n4 * 16 + l15) * 2) =
                        f2bf(siluf(acc[nt][rr]));
            }
            #pragma unroll
            for (int k2 = 0; k2 < 2; ++k2)
                ha[ph * 2 + k2] = *(const short8*)swz64(sH[w], l15, k2 * 64 + quad * 16);
        }
        floatx4 acc2[8];
        #pragma unroll
        for (int nt = 0; nt < 8; ++nt) acc2[nt] = (floatx4){0.f, 0.f, 0.f, 0.f};
        #pragma unroll
        for (int ks = 0; ks < 4; ++ks)
            #pragma unroll
            for (int nt = 0; nt < 8; ++nt) {
                short8 bv = *(const short8*)swzp(sW2, nt * 16 + l15, ks * 64 + quad * 16);
                acc2[nt] = __builtin_amdgcn_mfma_f32_16x16x32_bf16(ha[ks], bv, acc2[nt], 0, 0, 0);
            }
        // LN -> new_node bf16 -> split transpose -> h2
        float sum[4] = {0, 0, 0, 0}, sq[4] = {0, 0, 0, 0};
        #pragma unroll
        for (int nt = 0; nt < 8; ++nt)
            #pragma unroll
            for (int rr = 0; rr < 4; ++rr) {
                float v = acc2[nt][rr] + b2r[nt];
                acc2[nt][rr] = v; sum[rr] += v; sq[rr] += v * v;
            }
        #pragma unroll
        for (int m = 1; m < 16; m <<= 1)
            #pragma unroll
            for (int rr = 0; rr < 4; ++rr) {
                sum[rr] += __shfl_xor(sum[rr], m);
                sq[rr]  += __shfl_xor(sq[rr], m);
            }
        float mu[4], rs[4];
        #pragma unroll
        for (int rr = 0; rr < 4; ++rr) {
            mu[rr] = sum[rr] * (1.0f / HID);
            float var = fmaxf(sq[rr] * (1.0f / HID) - mu[rr] * mu[rr], 0.f);
            rs[rr] = rsqrtf(var + LN_EPS);
        }
        short8 h2[4];
        #pragma unroll
        for (int ph = 0; ph < 2; ++ph) {
            #pragma unroll
            for (int n4 = 0; n4 < 4; ++n4) {
                int nt = ph * 4 + n4;
                #pragma unroll
                for (int rr = 0; rr < 4; ++rr)
                    *(u16*)swz64(sH[w], quad * 4 + rr, (n4 * 16 + l15) * 2) =
                        f2bf((acc2[nt][rr] - mu[rr]) * rs[rr] * gr[nt] + ber[nt]);
            }
            #pragma unroll
            for (int k2 = 0; k2 < 2; ++k2)
                h2[ph * 2 + k2] = *(const short8*)swz64(sH[w], l15, k2 * 64 + quad * 16);
        }
        floatx4 acc3[8];
        #pragma unroll
        for (int nt = 0; nt < 8; ++nt) acc3[nt] = (floatx4){0.f, 0.f, 0.f, 0.f};
        #pragma unroll
        for (int ks = 0; ks < 4; ++ks)
            #pragma unroll
            for (int nt = 0; nt < 8; ++nt) {   // noW1 B-frags from global (L1-resident)
                short8 bv = *(const short8*)&noW1T[(size_t)(nt * 16 + l15) * 128 +
                                                   ks * 32 + quad * 8];
                acc3[nt] = __builtin_amdgcn_mfma_f32_16x16x32_bf16(h2[ks], bv, acc3[nt], 0, 0, 0);
            }
        float p[4][3] = {{0,0,0},{0,0,0},{0,0,0},{0,0,0}};
        #pragma unroll
        for (int nt = 0; nt < 8; ++nt)
            #pragma unroll
            for (int rr = 0; rr < 4; ++rr) {
                float h3 = sigmf(acc3[nt][rr] + nob1r[nt]);
                #pragma unroll
                for (int c = 0; c < 3; ++c) p[rr][c] += h3 * w2r[nt][c];
            }
        #pragma unroll
        for (int m = 1; m < 16; m <<= 1)
            #pragma unroll
            for (int rr = 0; rr < 4; ++rr)
                #pragma unroll
                for (int c = 0; c < 3; ++c) p[rr][c] += __shfl_xor(p[rr][c], m);
        if (l15 < 3) {
            #pragma unroll
            for (int rr = 0; rr < 4; ++rr)
                if (crow[rr] < N_NODES)
                    outN[(size_t)crow[rr] * 3 + l15] = p[rr][l15] + nob2r[l15];
        }
    }
}

extern "C" void kernel_launch(void* const* d_in, const int* in_sizes, int n_in,
                              void* d_out, int out_size, void* d_ws, size_t ws_size,
                              hipStream_t stream) {
    const int*   eidx  = (const int*)d_in[0];
    const float* ef    = (const float*)d_in[1];
    const float* nlat  = (const float*)d_in[2];
    const float* nfeat = (const float*)d_in[3];
    const float* eeW1 = (const float*)d_in[4];
    const float* eeb1 = (const float*)d_in[5];
    const float* eeW2 = (const float*)d_in[6];
    const float* eeb2 = (const float*)d_in[7];
    const float* eeg  = (const float*)d_in[8];
    const float* eebe = (const float*)d_in[9];
    const float* peW1 = (const float*)d_in[10];
    const float* peb1 = (const float*)d_in[11];
    const float* peW2 = (const float*)d_in[12];
    const float* peb2 = (const float*)d_in[13];
    const float* peg  = (const float*)d_in[14];
    const float* pebe = (const float*)d_in[15];
    const float* pnW1 = (const float*)d_in[16];
    const float* pnb1 = (const float*)d_in[17];
    const float* pnW2 = (const float*)d_in[18];
    const float* pnb2 = (const float*)d_in[19];
    const float* png_ = (const float*)d_in[20];
    const float* pnbe = (const float*)d_in[21];
    const float* noW1 = (const float*)d_in[22];
    const float* nob1 = (const float*)d_in[23];
    const float* noW2 = (const float*)d_in[24];
    const float* nob2 = (const float*)d_in[25];

    float* outEL = (float*)d_out;
    float* outN  = outEL + (size_t)N_EDGES * HID;
    char* ws = (char*)d_ws;

    // 256B-aligned big arrays (r8 lesson: misaligned rows -> partial-sector RMW)
    u16*  eeW2T = (u16*)(ws + 0);          //     32,768
    u16*  peW1T = (u16*)(ws + 32768);      //     98,304
    u16*  peW2T = (u16*)(ws + 131072);     //     32,768
    u16*  pnW1T = (u16*)(ws + 163840);     //     65,536
    u16*  pnW2T = (u16*)(ws + 229376);     //     32,768
    u16*  noW1T = (u16*)(ws + 262144);     //     32,768
    int*  icnt  = (int*)(ws + 294912);     //    200,000
    int*  offs  = (int*)(ws + 494912);     //    200,004
    int*  fpos  = (int*)(ws + 694920);     //    200,000
    int2* csrES = (int2*)(ws + 894920);    //  3,200,000
    u16*  P1    = (u16*)(ws + 4096000);    // 12,800,000 (permuted; also Q1)
    u16*  P2    = (u16*)(ws + 16896000);   // 12,800,000 (permuted)
    u16*  meanB = (u16*)(ws + 29696000);   // 12,800,000 -> end 42,496,000 (< 51.7MB proven)

    hipMemsetAsync(ws + 294912, 0, 600008, stream);   // icnt + offs + fpos

    k_prepT<<<64, 256, 0, stream>>>(eeW2, eeW2T, 128, 128);
    k_prepT<<<192, 256, 0, stream>>>(peW1, peW1T, 384, 128);
    k_prepT<<<64, 256, 0, stream>>>(peW2, peW2T, 128, 128);
    k_prepT<<<128, 256, 0, stream>>>(pnW1, pnW1T, 256, 128);
    k_prepT<<<64, 256, 0, stream>>>(pnW2, pnW2T, 128, 128);
    k_prepT<<<64, 256, 0, stream>>>(noW1, noW1T, 128, 128);

    k_hist<<<782, 512, 0, stream>>>(eidx, icnt);
    k_scan<<<1, 1024, 0, stream>>>(icnt, offs);
    k_fill<<<782, 512, 0, stream>>>(eidx, offs, fpos, csrES);

    k_edge_ee<<<1024, 256, 0, stream>>>(ef, eeW1, eeb1, eeW2T, eeb2, eeg, eebe, outEL);
    k_gemm128<<<512, 256, 0, stream>>>(nlat,  peW1T, 384, 0,   P1);   // P1 = nlat@peW1a
    k_gemm128<<<512, 256, 0, stream>>>(nfeat, peW1T, 384, 128, P2);   // P2 = nfeat@peW1b

    k_pe_node<<<1024, 256, 0, stream>>>(csrES, offs, P1, P2, outEL, peW1T, peb1,
                                        peW2T, peb2, peg, pebe, meanB);

    k_gemm128<<<512, 256, 0, stream>>>(nfeat, pnW1T, 256, 0, P1);     // Q1 = nfeat@pnW1a
    k_node<<<391, 512, 0, stream>>>(P1, meanB, pnW1T, pnb1, pnW2T, pnb2, png_, pnbe,
                                    noW1T, nob1, noW2, nob2, outN);
}